// Round 1
// baseline (1985.960 us; speedup 1.0000x reference)
//
#include <hip/hip_runtime.h>
#include <hip/hip_bf16.h>

// Transformer-XL relative MHA. S=1024, P=1024, B=4, E=1024, H=16, I=64, J=P+S=2048.
// Round 0: correct fp32 GEMMs + bf16-LDS flash attention baseline.

__device__ __forceinline__ unsigned short f2bf(float f) {
    unsigned int u = __float_as_uint(f);
    u = u + 0x7fffu + ((u >> 16) & 1u);   // RNE
    return (unsigned short)(u >> 16);
}
__device__ __forceinline__ void expand2(unsigned int u, float& lo, float& hi) {
    lo = __uint_as_float(u << 16);
    hi = __uint_as_float(u & 0xffff0000u);
}

// ---------------------------------------------------------------------------
// Generic C = A @ W^T, K=1024, tile 128x128, BK=16, 8x8 per thread, fp32.
// MODE 0: kv   (A rows = concat(memory,inputMHA) at batch b; N=2048 -> K/V (B,H,J,I))
// MODE 1: q    (rows (s,b); writes qu=q+u, qv=q+v as (B,H,S,I))
// MODE 2: pv   (rows j; writes Pv as (H,J,I))
// MODE 3: out  (rows (s,b); += residual inputMHA; writes d_out flat (S,B,E))
// ---------------------------------------------------------------------------
template<int MODE>
__global__ __launch_bounds__(256, 2)
void gemm_nt(const float* __restrict__ A0, const float* __restrict__ A1,
             const float* __restrict__ W,
             const float* __restrict__ aux0, const float* __restrict__ aux1,
             float* __restrict__ out0, float* __restrict__ out1)
{
    __shared__ float As[16 * 132];
    __shared__ float Ws[16 * 132];
    const int tid = threadIdx.x;
    const int ty = tid >> 4, tx = tid & 15;
    const int m0 = blockIdx.x * 128;
    const int n0 = blockIdx.y * 128;
    const int b  = blockIdx.z;

    float acc[8][8];
    #pragma unroll
    for (int i = 0; i < 8; ++i)
        #pragma unroll
        for (int j = 0; j < 8; ++j) acc[i][j] = 0.f;

    for (int k0 = 0; k0 < 1024; k0 += 16) {
        __syncthreads();
        #pragma unroll
        for (int q = 0; q < 2; ++q) {
            int idx = tid + q * 256;          // 0..511 float4 slots
            int row = idx >> 2;               // 0..127
            int kq  = (idx & 3) << 2;         // 0,4,8,12
            int m = m0 + row;
            const float* ap;
            if (MODE == 0) {
                ap = (m < 1024) ? (A0 + ((size_t)m * 4 + b) * 1024)
                                : (A1 + ((size_t)(m - 1024) * 4 + b) * 1024);
            } else {
                ap = A0 + (size_t)m * 1024;
            }
            float4 av = *(const float4*)(ap + k0 + kq);
            As[(kq + 0) * 132 + row] = av.x;
            As[(kq + 1) * 132 + row] = av.y;
            As[(kq + 2) * 132 + row] = av.z;
            As[(kq + 3) * 132 + row] = av.w;
            float4 wv = *(const float4*)(W + (size_t)(n0 + row) * 1024 + k0 + kq);
            Ws[(kq + 0) * 132 + row] = wv.x;
            Ws[(kq + 1) * 132 + row] = wv.y;
            Ws[(kq + 2) * 132 + row] = wv.z;
            Ws[(kq + 3) * 132 + row] = wv.w;
        }
        __syncthreads();
        #pragma unroll
        for (int kk = 0; kk < 16; ++kk) {
            float4 a0 = *(const float4*)&As[kk * 132 + ty * 8];
            float4 a1 = *(const float4*)&As[kk * 132 + ty * 8 + 4];
            float4 b0 = *(const float4*)&Ws[kk * 132 + tx * 8];
            float4 b1 = *(const float4*)&Ws[kk * 132 + tx * 8 + 4];
            float ar[8] = {a0.x, a0.y, a0.z, a0.w, a1.x, a1.y, a1.z, a1.w};
            float br[8] = {b0.x, b0.y, b0.z, b0.w, b1.x, b1.y, b1.z, b1.w};
            #pragma unroll
            for (int i = 0; i < 8; ++i)
                #pragma unroll
                for (int j = 0; j < 8; ++j)
                    acc[i][j] += ar[i] * br[j];
        }
    }

    #pragma unroll
    for (int i = 0; i < 8; ++i) {
        int m = m0 + ty * 8 + i;
        #pragma unroll
        for (int jj = 0; jj < 8; jj += 4) {
            int n = n0 + tx * 8 + jj;
            float4 val = make_float4(acc[i][jj], acc[i][jj+1], acc[i][jj+2], acc[i][jj+3]);
            if (MODE == 0) {
                int isV = (n >= 1024);
                int nn = n & 1023;
                int h = nn >> 6, ii = nn & 63;
                float* dst = (isV ? out1 : out0) + (((size_t)(b * 16 + h) * 2048 + m) * 64 + ii);
                *(float4*)dst = val;
            } else if (MODE == 1) {
                int s = m >> 2, bb = m & 3;
                int h = n >> 6, ii = n & 63;
                float4 uu = *(const float4*)(aux0 + n);
                float4 vv = *(const float4*)(aux1 + n);
                size_t base = ((size_t)(bb * 16 + h) * 1024 + s) * 64 + ii;
                *(float4*)(out0 + base) = make_float4(val.x + uu.x, val.y + uu.y, val.z + uu.z, val.w + uu.w);
                *(float4*)(out1 + base) = make_float4(val.x + vv.x, val.y + vv.y, val.z + vv.z, val.w + vv.w);
            } else if (MODE == 2) {
                int h = n >> 6, ii = n & 63;
                *(float4*)(out0 + (size_t)h * 131072 + (size_t)m * 64 + ii) = val;
            } else {
                float4 res = *(const float4*)(aux0 + (size_t)m * 1024 + n);
                *(float4*)(out0 + (size_t)m * 1024 + n) =
                    make_float4(val.x + res.x, val.y + res.y, val.z + res.z, val.w + res.w);
            }
        }
    }
}

// ---------------------------------------------------------------------------
// Flash attention with Transformer-XL rel-shift.
// score[s,j] = 0.125*(qu_s.K_j + qv_s.Pv[j+1023-s]), masked j > P+s.
// Block: (s-tile of 64, h, b); 256 thr (16x16), 4x4 micro-tile; online softmax.
// bf16 LDS tiles (fp32 accum). K/V/Pv XOR-swizzled (stride-128B rows otherwise
// put all strided-row lane reads in one bank).
// ---------------------------------------------------------------------------
__global__ __launch_bounds__(256, 2)
void attn_kernel(const float* __restrict__ quG, const float* __restrict__ qvG,
                 const float* __restrict__ Kg, const float* __restrict__ Vg,
                 const float* __restrict__ Pvg, float* __restrict__ ctx)
{
    const int st = blockIdx.x, h = blockIdx.y, b = blockIdx.z;
    const int s0 = st << 6;
    const int tid = threadIdx.x;
    const int ty = tid >> 4, tx = tid & 15;
    const int qrow = ty << 2, kcol = tx << 2;

    __shared__ unsigned short Qu_s[64 * 72];
    __shared__ unsigned short Qv_s[64 * 72];
    __shared__ unsigned short KV_s[64 * 64];    // K in score phase, V in PV phase
    __shared__ unsigned short Pv_s[128 * 64];   // shifted-position window
    __shared__ float P_s[64 * 68];

    const size_t bh = (size_t)b * 16 + h;
    const float* quP = quG + bh * 65536;
    const float* qvP = qvG + bh * 65536;
    const float* kP  = Kg  + bh * 131072;
    const float* vP  = Vg  + bh * 131072;
    const float* pvP = Pvg + (size_t)h * 131072;

    #pragma unroll
    for (int q = 0; q < 4; ++q) {
        int idx = tid + q * 256;
        int row = idx >> 4;
        int c4  = (idx & 15) << 2;
        float4 f = *(const float4*)(quP + (size_t)(s0 + row) * 64 + c4);
        unsigned short* d0 = &Qu_s[row * 72 + c4];
        d0[0] = f2bf(f.x); d0[1] = f2bf(f.y); d0[2] = f2bf(f.z); d0[3] = f2bf(f.w);
        f = *(const float4*)(qvP + (size_t)(s0 + row) * 64 + c4);
        unsigned short* d1 = &Qv_s[row * 72 + c4];
        d1[0] = f2bf(f.x); d1[1] = f2bf(f.y); d1[2] = f2bf(f.z); d1[3] = f2bf(f.w);
    }

    float acc_o[4][4];
    float m_run[4], l_run[4];
    #pragma unroll
    for (int r = 0; r < 4; ++r) {
        m_run[r] = -1e30f; l_run[r] = 0.f;
        #pragma unroll
        for (int c = 0; c < 4; ++c) acc_o[r][c] = 0.f;
    }

    const int numTiles = 17 + st;            // last needed j-tile index = 16+st
    const int baseRow = kcol - qrow + 63;    // Pv local row = baseRow + (c - r)

    for (int t = 0; t < numTiles; ++t) {
        const int j0 = t << 6;
        __syncthreads();   // previous tile's PV reads done before restaging

        #pragma unroll
        for (int q = 0; q < 4; ++q) {        // stage K (swizzled bf16)
            int idx = tid + q * 256;
            int row = idx >> 4;
            int c4  = (idx & 15) << 2;
            float4 f = *(const float4*)(kP + (size_t)(j0 + row) * 64 + c4);
            int col = c4 ^ (((row >> 2) & 7) << 3);
            uint2 pk;
            pk.x = (unsigned int)f2bf(f.x) | ((unsigned int)f2bf(f.y) << 16);
            pk.y = (unsigned int)f2bf(f.z) | ((unsigned int)f2bf(f.w) << 16);
            *(uint2*)&KV_s[row * 64 + col] = pk;
        }
        const int pvBase = j0 + 960 - s0;    // window start; rows >= 2048 -> 0
        #pragma unroll
        for (int q = 0; q < 8; ++q) {        // stage Pv window (128 rows)
            int idx = tid + q * 256;
            int row = idx >> 4;
            int c4  = (idx & 15) << 2;
            int g = pvBase + row;
            float4 f = make_float4(0.f, 0.f, 0.f, 0.f);
            if (g < 2048) f = *(const float4*)(pvP + (size_t)g * 64 + c4);
            int col = c4 ^ (((row >> 2) & 7) << 3);
            uint2 pk;
            pk.x = (unsigned int)f2bf(f.x) | ((unsigned int)f2bf(f.y) << 16);
            pk.y = (unsigned int)f2bf(f.z) | ((unsigned int)f2bf(f.w) << 16);
            *(uint2*)&Pv_s[row * 64 + col] = pk;
        }
        __syncthreads();

        float sc[4][4];
        #pragma unroll
        for (int r = 0; r < 4; ++r)
            #pragma unroll
            for (int c = 0; c < 4; ++c) sc[r][c] = 0.f;

        for (int k8 = 0; k8 < 64; k8 += 8) {
            uint4 a4[4], b4[4];
            #pragma unroll
            for (int r = 0; r < 4; ++r) a4[r] = *(const uint4*)&Qu_s[(qrow + r) * 72 + k8];
            #pragma unroll
            for (int c = 0; c < 4; ++c) {
                int row = kcol + c;
                b4[c] = *(const uint4*)&KV_s[row * 64 + (k8 ^ (((row >> 2) & 7) << 3))];
            }
            #pragma unroll
            for (int w = 0; w < 4; ++w) {
                float al[4], ah[4], bl[4], bh2[4];
                #pragma unroll
                for (int r = 0; r < 4; ++r) expand2(((const unsigned int*)&a4[r])[w], al[r], ah[r]);
                #pragma unroll
                for (int c = 0; c < 4; ++c) expand2(((const unsigned int*)&b4[c])[w], bl[c], bh2[c]);
                #pragma unroll
                for (int r = 0; r < 4; ++r)
                    #pragma unroll
                    for (int c = 0; c < 4; ++c)
                        sc[r][c] += al[r] * bl[c] + ah[r] * bh2[c];
            }
            uint4 p7[7];
            #pragma unroll
            for (int d = 0; d < 7; ++d) {    // 7 shared diagonals: row = baseRow + (c-r)
                int row = baseRow + d - 3;
                p7[d] = *(const uint4*)&Pv_s[row * 64 + (k8 ^ (((row >> 2) & 7) << 3))];
            }
            #pragma unroll
            for (int r = 0; r < 4; ++r) a4[r] = *(const uint4*)&Qv_s[(qrow + r) * 72 + k8];
            #pragma unroll
            for (int w = 0; w < 4; ++w) {
                float al[4], ah[4], pl[7], ph[7];
                #pragma unroll
                for (int r = 0; r < 4; ++r) expand2(((const unsigned int*)&a4[r])[w], al[r], ah[r]);
                #pragma unroll
                for (int d = 0; d < 7; ++d) expand2(((const unsigned int*)&p7[d])[w], pl[d], ph[d]);
                #pragma unroll
                for (int r = 0; r < 4; ++r)
                    #pragma unroll
                    for (int c = 0; c < 4; ++c)
                        sc[r][c] += al[r] * pl[c - r + 3] + ah[r] * ph[c - r + 3];
            }
        }

        // scale + causal mask + online softmax (row stats across 16 tx lanes)
        float mt[4];
        #pragma unroll
        for (int r = 0; r < 4; ++r) {
            int s_abs = s0 + qrow + r;
            float rm = -1e30f;
            #pragma unroll
            for (int c = 0; c < 4; ++c) {
                int j_abs = j0 + kcol + c;
                float vsc = sc[r][c] * 0.125f;
                if (j_abs > 1024 + s_abs) vsc = -1e30f;
                sc[r][c] = vsc;
                rm = fmaxf(rm, vsc);
            }
            mt[r] = rm;
        }
        #pragma unroll
        for (int r = 0; r < 4; ++r)
            #pragma unroll
            for (int off = 1; off < 16; off <<= 1)
                mt[r] = fmaxf(mt[r], __shfl_xor(mt[r], off, 64));

        #pragma unroll
        for (int r = 0; r < 4; ++r) {
            float mn = fmaxf(m_run[r], mt[r]);
            float alpha = __expf(m_run[r] - mn);
            m_run[r] = mn;
            float p0 = __expf(sc[r][0] - mn);
            float p1 = __expf(sc[r][1] - mn);
            float p2 = __expf(sc[r][2] - mn);
            float p3 = __expf(sc[r][3] - mn);
            *(float4*)&P_s[(qrow + r) * 68 + kcol] = make_float4(p0, p1, p2, p3);
            float ls = p0 + p1 + p2 + p3;
            #pragma unroll
            for (int off = 1; off < 16; off <<= 1)
                ls += __shfl_xor(ls, off, 64);
            l_run[r] = l_run[r] * alpha + ls;
            #pragma unroll
            for (int c = 0; c < 4; ++c) acc_o[r][c] *= alpha;
        }
        __syncthreads();   // P_s complete; K reads done -> safe to overwrite KV_s

        #pragma unroll
        for (int q = 0; q < 4; ++q) {        // stage V
            int idx = tid + q * 256;
            int row = idx >> 4;
            int c4  = (idx & 15) << 2;
            float4 f = *(const float4*)(vP + (size_t)(j0 + row) * 64 + c4);
            int col = c4 ^ (((row >> 2) & 7) << 3);
            uint2 pk;
            pk.x = (unsigned int)f2bf(f.x) | ((unsigned int)f2bf(f.y) << 16);
            pk.y = (unsigned int)f2bf(f.z) | ((unsigned int)f2bf(f.w) << 16);
            *(uint2*)&KV_s[row * 64 + col] = pk;
        }
        __syncthreads();

        for (int kj8 = 0; kj8 < 64; kj8 += 8) {   // ctx += P @ V
            float pr[4][8];
            #pragma unroll
            for (int r = 0; r < 4; ++r) {
                float4 x0 = *(const float4*)&P_s[(qrow + r) * 68 + kj8];
                float4 x1 = *(const float4*)&P_s[(qrow + r) * 68 + kj8 + 4];
                pr[r][0] = x0.x; pr[r][1] = x0.y; pr[r][2] = x0.z; pr[r][3] = x0.w;
                pr[r][4] = x1.x; pr[r][5] = x1.y; pr[r][6] = x1.z; pr[r][7] = x1.w;
            }
            #pragma unroll
            for (int kk = 0; kk < 8; ++kk) {
                int vrow = kj8 + kk;
                uint2 vv = *(const uint2*)&KV_s[vrow * 64 + (kcol ^ (((vrow >> 2) & 7) << 3))];
                float v0, v1, v2, v3;
                expand2(vv.x, v0, v1);
                expand2(vv.y, v2, v3);
                #pragma unroll
                for (int r = 0; r < 4; ++r) {
                    float p = pr[r][kk];
                    acc_o[r][0] += p * v0;
                    acc_o[r][1] += p * v1;
                    acc_o[r][2] += p * v2;
                    acc_o[r][3] += p * v3;
                }
            }
        }
    }

    #pragma unroll
    for (int r = 0; r < 4; ++r) {
        float inv = 1.0f / l_run[r];
        size_t dst = ((size_t)(s0 + qrow + r) * 4 + b) * 1024 + h * 64 + kcol;
        *(float4*)(ctx + dst) =
            make_float4(acc_o[r][0] * inv, acc_o[r][1] * inv, acc_o[r][2] * inv, acc_o[r][3] * inv);
    }
}

// In-place LayerNorm over E=1024 per row; one block per (s,b) row.
__global__ __launch_bounds__(256)
void ln_kernel(float* __restrict__ io, const float* __restrict__ w, const float* __restrict__ bvec)
{
    int row = blockIdx.x;
    float* p = io + (size_t)row * 1024;
    int tid = threadIdx.x;
    float4 v = *(const float4*)(p + tid * 4);
    float s  = v.x + v.y + v.z + v.w;
    float s2 = v.x * v.x + v.y * v.y + v.z * v.z + v.w * v.w;
    #pragma unroll
    for (int off = 1; off < 64; off <<= 1) {
        s  += __shfl_xor(s,  off, 64);
        s2 += __shfl_xor(s2, off, 64);
    }
    __shared__ float red[8];
    int wv = tid >> 6;
    if ((tid & 63) == 0) { red[wv] = s; red[wv + 4] = s2; }
    __syncthreads();
    s  = red[0] + red[1] + red[2] + red[3];
    s2 = red[4] + red[5] + red[6] + red[7];
    float mu  = s * (1.0f / 1024.0f);
    float var = s2 * (1.0f / 1024.0f) - mu * mu;
    float rstd = rsqrtf(var + 1e-5f);
    float4 w4 = *(const float4*)(w + tid * 4);
    float4 b4 = *(const float4*)(bvec + tid * 4);
    float4 o;
    o.x = (v.x - mu) * rstd * w4.x + b4.x;
    o.y = (v.y - mu) * rstd * w4.y + b4.y;
    o.z = (v.z - mu) * rstd * w4.z + b4.z;
    o.w = (v.w - mu) * rstd * w4.w + b4.w;
    *(float4*)(p + tid * 4) = o;
}

extern "C" void kernel_launch(void* const* d_in, const int* in_sizes, int n_in,
                              void* d_out, int out_size, void* d_ws, size_t ws_size,
                              hipStream_t stream)
{
    const float* inputMHA = (const float*)d_in[0];
    const float* posEmb   = (const float*)d_in[1];
    const float* memory   = (const float*)d_in[2];
    const float* u        = (const float*)d_in[3];
    const float* v        = (const float*)d_in[4];
    const float* W_kv     = (const float*)d_in[5];
    const float* W_q      = (const float*)d_in[6];
    const float* W_p      = (const float*)d_in[7];
    const float* W_out    = (const float*)d_in[8];
    const float* ln_w     = (const float*)d_in[9];
    const float* ln_b     = (const float*)d_in[10];
    float* out = (float*)d_out;

    // workspace layout (floats)
    float* ws  = (float*)d_ws;
    float* Kg  = ws;                    // (B,H,J,I)  8388608
    float* Vg  = Kg + 8388608;          // (B,H,J,I)  8388608
    float* qu  = Vg + 8388608;          // (B,H,S,I)  4194304
    float* qv  = qu + 4194304;          // (B,H,S,I)  4194304
    float* Pv  = qv + 4194304;          // (H,J,I)    2097152
    float* ctx = Pv + 2097152;          // (S,B,H*I)  4194304
    if (ws_size < (size_t)31457280 * 4) return;   // 120 MB needed

    gemm_nt<0><<<dim3(16, 16, 4), 256, 0, stream>>>(memory, inputMHA, W_kv, nullptr, nullptr, Kg, Vg);
    gemm_nt<1><<<dim3(32, 8, 1),  256, 0, stream>>>(inputMHA, nullptr, W_q, u, v, qu, qv);
    gemm_nt<2><<<dim3(16, 8, 1),  256, 0, stream>>>(posEmb, nullptr, W_p, nullptr, nullptr, Pv, nullptr);
    attn_kernel<<<dim3(16, 16, 4), 256, 0, stream>>>(qu, qv, Kg, Vg, Pv, ctx);
    gemm_nt<3><<<dim3(32, 8, 1),  256, 0, stream>>>(ctx, nullptr, W_out, inputMHA, nullptr, out, nullptr);
    ln_kernel<<<dim3(4096, 1, 1), 256, 0, stream>>>(out, ln_w, ln_b);
}

// Round 2
// 1318.800 us; speedup vs baseline: 1.5059x; 1.5059x over previous
//
#include <hip/hip_runtime.h>
#include <hip/hip_bf16.h>

// Transformer-XL relative MHA. S=1024, P=1024, B=4, E=1024, H=16, I=64, J=2048.
// R1: MFMA bf16 flash attention; producers emit bf16 workspace; fp32 GEMMs.

typedef __bf16 bf16x8 __attribute__((ext_vector_type(8)));
typedef float f32x4 __attribute__((ext_vector_type(4)));

__device__ __forceinline__ unsigned short f2bf(float f) {
    unsigned int u = __float_as_uint(f);
    u = u + 0x7fffu + ((u >> 16) & 1u);   // RNE
    return (unsigned short)(u >> 16);
}
__device__ __forceinline__ bf16x8 ldfrag(const unsigned short* p) {
    uint4 u = *(const uint4*)p;
    return __builtin_bit_cast(bf16x8, u);
}
__device__ __forceinline__ bf16x8 castfrag(uint4 u) {
    return __builtin_bit_cast(bf16x8, u);
}

// ---------------------------------------------------------------------------
// C = A @ W^T, K=1024, tile 128x128, BK=16, 8x8 per thread, fp32 compute.
// MODE 0: kv  -> K,V bf16 (B,H,J,I)
// MODE 1: q   -> qu=q+u, qv=q+v bf16 (B,H,S,I)
// MODE 2: pv  -> Pv bf16 (H,J,I)
// MODE 3: out -> += residual, fp32 (S,B,E)
// ---------------------------------------------------------------------------
template<int MODE>
__global__ __launch_bounds__(256, 2)
void gemm_nt(const float* __restrict__ A0, const float* __restrict__ A1,
             const float* __restrict__ W,
             const float* __restrict__ aux0, const float* __restrict__ aux1,
             void* __restrict__ o0, void* __restrict__ o1)
{
    __shared__ float As[16 * 132];
    __shared__ float Ws[16 * 132];
    const int tid = threadIdx.x;
    const int ty = tid >> 4, tx = tid & 15;
    const int m0 = blockIdx.x * 128;
    const int n0 = blockIdx.y * 128;
    const int b  = blockIdx.z;

    float acc[8][8];
    #pragma unroll
    for (int i = 0; i < 8; ++i)
        #pragma unroll
        for (int j = 0; j < 8; ++j) acc[i][j] = 0.f;

    for (int k0 = 0; k0 < 1024; k0 += 16) {
        __syncthreads();
        #pragma unroll
        for (int q = 0; q < 2; ++q) {
            int idx = tid + q * 256;
            int row = idx >> 2;
            int kq  = (idx & 3) << 2;
            int m = m0 + row;
            const float* ap;
            if (MODE == 0) {
                ap = (m < 1024) ? (A0 + ((size_t)m * 4 + b) * 1024)
                                : (A1 + ((size_t)(m - 1024) * 4 + b) * 1024);
            } else {
                ap = A0 + (size_t)m * 1024;
            }
            float4 av = *(const float4*)(ap + k0 + kq);
            As[(kq + 0) * 132 + row] = av.x;
            As[(kq + 1) * 132 + row] = av.y;
            As[(kq + 2) * 132 + row] = av.z;
            As[(kq + 3) * 132 + row] = av.w;
            float4 wv = *(const float4*)(W + (size_t)(n0 + row) * 1024 + k0 + kq);
            Ws[(kq + 0) * 132 + row] = wv.x;
            Ws[(kq + 1) * 132 + row] = wv.y;
            Ws[(kq + 2) * 132 + row] = wv.z;
            Ws[(kq + 3) * 132 + row] = wv.w;
        }
        __syncthreads();
        #pragma unroll
        for (int kk = 0; kk < 16; ++kk) {
            float4 a0 = *(const float4*)&As[kk * 132 + ty * 8];
            float4 a1 = *(const float4*)&As[kk * 132 + ty * 8 + 4];
            float4 b0 = *(const float4*)&Ws[kk * 132 + tx * 8];
            float4 b1 = *(const float4*)&Ws[kk * 132 + tx * 8 + 4];
            float ar[8] = {a0.x, a0.y, a0.z, a0.w, a1.x, a1.y, a1.z, a1.w};
            float br[8] = {b0.x, b0.y, b0.z, b0.w, b1.x, b1.y, b1.z, b1.w};
            #pragma unroll
            for (int i = 0; i < 8; ++i)
                #pragma unroll
                for (int j = 0; j < 8; ++j)
                    acc[i][j] += ar[i] * br[j];
        }
    }

    #pragma unroll
    for (int i = 0; i < 8; ++i) {
        int m = m0 + ty * 8 + i;
        #pragma unroll
        for (int jj = 0; jj < 8; jj += 4) {
            int n = n0 + tx * 8 + jj;
            float4 val = make_float4(acc[i][jj], acc[i][jj+1], acc[i][jj+2], acc[i][jj+3]);
            if (MODE == 0) {
                int isV = (n >= 1024);
                int nn = n & 1023;
                int h = nn >> 6, ii = nn & 63;
                unsigned short* dst = (unsigned short*)(isV ? o1 : o0)
                    + (((size_t)(b * 16 + h) * 2048 + m) * 64 + ii);
                uint2 pk;
                pk.x = f2bf(val.x) | ((unsigned int)f2bf(val.y) << 16);
                pk.y = f2bf(val.z) | ((unsigned int)f2bf(val.w) << 16);
                *(uint2*)dst = pk;
            } else if (MODE == 1) {
                int s = m >> 2, bb = m & 3;
                int h = n >> 6, ii = n & 63;
                float4 uu = *(const float4*)(aux0 + n);
                float4 vv = *(const float4*)(aux1 + n);
                size_t base = ((size_t)(bb * 16 + h) * 1024 + s) * 64 + ii;
                uint2 pk;
                pk.x = f2bf(val.x + uu.x) | ((unsigned int)f2bf(val.y + uu.y) << 16);
                pk.y = f2bf(val.z + uu.z) | ((unsigned int)f2bf(val.w + uu.w) << 16);
                *(uint2*)((unsigned short*)o0 + base) = pk;
                pk.x = f2bf(val.x + vv.x) | ((unsigned int)f2bf(val.y + vv.y) << 16);
                pk.y = f2bf(val.z + vv.z) | ((unsigned int)f2bf(val.w + vv.w) << 16);
                *(uint2*)((unsigned short*)o1 + base) = pk;
            } else if (MODE == 2) {
                int h = n >> 6, ii = n & 63;
                uint2 pk;
                pk.x = f2bf(val.x) | ((unsigned int)f2bf(val.y) << 16);
                pk.y = f2bf(val.z) | ((unsigned int)f2bf(val.w) << 16);
                *(uint2*)((unsigned short*)o0 + (size_t)h * 131072 + (size_t)m * 64 + ii) = pk;
            } else {
                float4 res = *(const float4*)(aux0 + (size_t)m * 1024 + n);
                *(float4*)((float*)o0 + (size_t)m * 1024 + n) =
                    make_float4(val.x + res.x, val.y + res.y, val.z + res.z, val.w + res.w);
            }
        }
    }
}

// Transpose V (b,h,j,i) -> Vt (b,h,i,j), bf16.
__global__ __launch_bounds__(256)
void vt_kernel(const unsigned short* __restrict__ Vg, unsigned short* __restrict__ Vt)
{
    const int jt = blockIdx.x, h = blockIdx.y, b = blockIdx.z;
    const int j0 = jt << 6;
    const size_t bh = (size_t)b * 16 + h;
    const unsigned short* src = Vg + bh * 131072;
    unsigned short* dst = Vt + bh * 131072;
    __shared__ unsigned short tile[64 * 68];
    const int tid = threadIdx.x;
    #pragma unroll
    for (int q = 0; q < 4; ++q) {
        int e = tid + q * 256;
        int row = e >> 4;
        int c4 = (e & 15) << 2;
        uint2 u = *(const uint2*)(src + (size_t)(j0 + row) * 64 + c4);
        tile[(c4 + 0) * 68 + row] = (unsigned short)(u.x & 0xffff);
        tile[(c4 + 1) * 68 + row] = (unsigned short)(u.x >> 16);
        tile[(c4 + 2) * 68 + row] = (unsigned short)(u.y & 0xffff);
        tile[(c4 + 3) * 68 + row] = (unsigned short)(u.y >> 16);
    }
    __syncthreads();
    #pragma unroll
    for (int q = 0; q < 4; ++q) {
        int e = tid + q * 256;
        int i = e >> 4;
        int c4 = (e & 15) << 2;
        uint2 u;
        u.x = (unsigned int)tile[i * 68 + c4]     | ((unsigned int)tile[i * 68 + c4 + 1] << 16);
        u.y = (unsigned int)tile[i * 68 + c4 + 2] | ((unsigned int)tile[i * 68 + c4 + 3] << 16);
        *(uint2*)(dst + (size_t)i * 2048 + j0 + c4) = u;
    }
}

// ---------------------------------------------------------------------------
// MFMA flash attention. Block = (s-tile 64, h, b), 4 waves; wave w owns rows
// 16w..16w+15. Per j-tile of 64: content QK^T (MFMA), windowed pos-GEMM T
// (MFMA, 128-row Pv window) -> LDS -> shift-gather, online softmax, P->LDS
// relayout (C->A frag), PV with pre-transposed Vt. No __syncthreads (per-wave
// LDS slices). mfma_f32_16x16x32_bf16: A/B k=8*(lane>>4)+e contiguous;
// C/D col=lane&15, row=4*(lane>>4)+reg.
// ---------------------------------------------------------------------------
__global__ __launch_bounds__(256, 3)
void attn_mfma(const unsigned short* __restrict__ quG, const unsigned short* __restrict__ qvG,
               const unsigned short* __restrict__ Kg, const unsigned short* __restrict__ Pvg,
               const unsigned short* __restrict__ Vt, float* __restrict__ ctx)
{
    const int st = blockIdx.x, h = blockIdx.y, b = blockIdx.z;
    const int s0 = st << 6;
    const int tid = threadIdx.x;
    const int w = tid >> 6, lane = tid & 63;
    const int lg = lane >> 4, ln = lane & 15;
    const int rowB = lg << 2;

    __shared__ float Ts[4][16 * 132];
    __shared__ unsigned short Ps[4][16 * 72];
    float* Tw = Ts[w];
    unsigned short* Pw = Ps[w];

    const size_t bh = (size_t)b * 16 + h;
    const unsigned short* quB = quG + bh * 65536;
    const unsigned short* qvB = qvG + bh * 65536;
    const unsigned short* kB  = Kg  + bh * 131072;
    const unsigned short* pvB = Pvg + (size_t)h * 131072;
    const unsigned short* vtB = Vt  + bh * 131072;

    const int srow = s0 + 16 * w + ln;
    bf16x8 quF[2], qvF[2];
    quF[0] = ldfrag(quB + (size_t)srow * 64 + 8 * lg);
    quF[1] = ldfrag(quB + (size_t)srow * 64 + 32 + 8 * lg);
    qvF[0] = ldfrag(qvB + (size_t)srow * 64 + 8 * lg);
    qvF[1] = ldfrag(qvB + (size_t)srow * 64 + 32 + 8 * lg);

    f32x4 accO[4];
    float m_run[4], l_run[4];
    #pragma unroll
    for (int r = 0; r < 4; ++r) {
        m_run[r] = -1e30f; l_run[r] = 0.f;
        accO[r] = (f32x4){0.f, 0.f, 0.f, 0.f};
    }

    const int nT = 17 + st;
    for (int t = 0; t < nT; ++t) {
        const int j0 = t << 6;
        const int pvBase = j0 + 960 - s0;

        // content scores: 4 col-frags
        f32x4 sC[4];
        #pragma unroll
        for (int fc = 0; fc < 4; ++fc) {
            const unsigned short* kp = kB + (size_t)(j0 + ln + 16 * fc) * 64 + 8 * lg;
            f32x4 z = {0.f, 0.f, 0.f, 0.f};
            z = __builtin_amdgcn_mfma_f32_16x16x32_bf16(quF[0], ldfrag(kp), z, 0, 0, 0);
            z = __builtin_amdgcn_mfma_f32_16x16x32_bf16(quF[1], ldfrag(kp + 32), z, 0, 0, 0);
            sC[fc] = z;
        }

        // windowed pos-GEMM T[s, r] over 128-row Pv window -> LDS
        #pragma unroll
        for (int rc = 0; rc < 8; ++rc) {
            int g = pvBase + ln + 16 * rc;
            uint4 u0 = make_uint4(0, 0, 0, 0), u1 = make_uint4(0, 0, 0, 0);
            if (g < 2048) {
                const unsigned short* pp = pvB + (size_t)g * 64 + 8 * lg;
                u0 = *(const uint4*)pp;
                u1 = *(const uint4*)(pp + 32);
            }
            f32x4 z = {0.f, 0.f, 0.f, 0.f};
            z = __builtin_amdgcn_mfma_f32_16x16x32_bf16(qvF[0], castfrag(u0), z, 0, 0, 0);
            z = __builtin_amdgcn_mfma_f32_16x16x32_bf16(qvF[1], castfrag(u1), z, 0, 0, 0);
            #pragma unroll
            for (int r = 0; r < 4; ++r)
                Tw[(rowB + r) * 132 + ln + 16 * rc] = z[r];
        }

        // gather shifted pos + combine + scale + mask
        float sc[4][4];
        #pragma unroll
        for (int fc = 0; fc < 4; ++fc) {
            int jc = ln + 16 * fc;
            int j_abs = j0 + jc;
            #pragma unroll
            for (int r = 0; r < 4; ++r) {
                int s_loc = 16 * w + rowB + r;
                int rr = jc - s_loc + 63;            // local Pv-window col
                float vv = (sC[fc][r] + Tw[(rowB + r) * 132 + rr]) * 0.125f;
                if (j_abs > 1024 + s0 + s_loc) vv = -1e30f;
                sc[fc][r] = vv;
            }
        }

        // online softmax per row (rows live in reg index r, spread over 16 ln lanes)
        #pragma unroll
        for (int r = 0; r < 4; ++r) {
            float mt = fmaxf(fmaxf(sc[0][r], sc[1][r]), fmaxf(sc[2][r], sc[3][r]));
            mt = fmaxf(mt, __shfl_xor(mt, 1, 64));
            mt = fmaxf(mt, __shfl_xor(mt, 2, 64));
            mt = fmaxf(mt, __shfl_xor(mt, 4, 64));
            mt = fmaxf(mt, __shfl_xor(mt, 8, 64));
            float mn = fmaxf(m_run[r], mt);
            float al = __expf(m_run[r] - mn);
            m_run[r] = mn;
            float rs = 0.f;
            #pragma unroll
            for (int fc = 0; fc < 4; ++fc) {
                float p = __expf(sc[fc][r] - mn);
                rs += p;
                Pw[(rowB + r) * 72 + ln + 16 * fc] = f2bf(p);
            }
            rs += __shfl_xor(rs, 1, 64);
            rs += __shfl_xor(rs, 2, 64);
            rs += __shfl_xor(rs, 4, 64);
            rs += __shfl_xor(rs, 8, 64);
            l_run[r] = l_run[r] * al + rs;
            #pragma unroll
            for (int fc = 0; fc < 4; ++fc) accO[fc][r] *= al;
        }

        // P: C-layout -> A-frags
        bf16x8 pa0 = ldfrag(Pw + ln * 72 + 8 * lg);
        bf16x8 pa1 = ldfrag(Pw + ln * 72 + 32 + 8 * lg);

        // PV with transposed V
        #pragma unroll
        for (int fc = 0; fc < 4; ++fc) {
            const unsigned short* vp = vtB + (size_t)(ln + 16 * fc) * 2048 + j0 + 8 * lg;
            accO[fc] = __builtin_amdgcn_mfma_f32_16x16x32_bf16(pa0, ldfrag(vp), accO[fc], 0, 0, 0);
            accO[fc] = __builtin_amdgcn_mfma_f32_16x16x32_bf16(pa1, ldfrag(vp + 32), accO[fc], 0, 0, 0);
        }
    }

    #pragma unroll
    for (int r = 0; r < 4; ++r) {
        float inv = 1.0f / l_run[r];
        #pragma unroll
        for (int fc = 0; fc < 4; ++fc) {
            size_t dst = ((size_t)(s0 + 16 * w + rowB + r) * 4 + b) * 1024 + h * 64 + ln + 16 * fc;
            ctx[dst] = accO[fc][r] * inv;
        }
    }
}

// In-place LayerNorm over E=1024 per row.
__global__ __launch_bounds__(256)
void ln_kernel(float* __restrict__ io, const float* __restrict__ w, const float* __restrict__ bvec)
{
    int row = blockIdx.x;
    float* p = io + (size_t)row * 1024;
    int tid = threadIdx.x;
    float4 v = *(const float4*)(p + tid * 4);
    float s  = v.x + v.y + v.z + v.w;
    float s2 = v.x * v.x + v.y * v.y + v.z * v.z + v.w * v.w;
    #pragma unroll
    for (int off = 1; off < 64; off <<= 1) {
        s  += __shfl_xor(s,  off, 64);
        s2 += __shfl_xor(s2, off, 64);
    }
    __shared__ float red[8];
    int wv = tid >> 6;
    if ((tid & 63) == 0) { red[wv] = s; red[wv + 4] = s2; }
    __syncthreads();
    s  = red[0] + red[1] + red[2] + red[3];
    s2 = red[4] + red[5] + red[6] + red[7];
    float mu  = s * (1.0f / 1024.0f);
    float var = s2 * (1.0f / 1024.0f) - mu * mu;
    float rstd = rsqrtf(var + 1e-5f);
    float4 w4 = *(const float4*)(w + tid * 4);
    float4 b4 = *(const float4*)(bvec + tid * 4);
    float4 o;
    o.x = (v.x - mu) * rstd * w4.x + b4.x;
    o.y = (v.y - mu) * rstd * w4.y + b4.y;
    o.z = (v.z - mu) * rstd * w4.z + b4.z;
    o.w = (v.w - mu) * rstd * w4.w + b4.w;
    *(float4*)(p + tid * 4) = o;
}

extern "C" void kernel_launch(void* const* d_in, const int* in_sizes, int n_in,
                              void* d_out, int out_size, void* d_ws, size_t ws_size,
                              hipStream_t stream)
{
    const float* inputMHA = (const float*)d_in[0];
    const float* posEmb   = (const float*)d_in[1];
    const float* memory   = (const float*)d_in[2];
    const float* u        = (const float*)d_in[3];
    const float* v        = (const float*)d_in[4];
    const float* W_kv     = (const float*)d_in[5];
    const float* W_q      = (const float*)d_in[6];
    const float* W_p      = (const float*)d_in[7];
    const float* W_out    = (const float*)d_in[8];
    const float* ln_w     = (const float*)d_in[9];
    const float* ln_b     = (const float*)d_in[10];
    float* out = (float*)d_out;

    // bf16 workspace
    unsigned short* wsh = (unsigned short*)d_ws;
    unsigned short* Kh  = wsh;                    // (B,H,J,I)  8388608
    unsigned short* Vh  = Kh  + 8388608;          // (B,H,J,I)
    unsigned short* VtH = Vh  + 8388608;          // (B,H,I,J)
    unsigned short* quH = VtH + 8388608;          // (B,H,S,I)  4194304
    unsigned short* qvH = quH + 4194304;          // (B,H,S,I)
    unsigned short* PvH = qvH + 4194304;          // (H,J,I)    2097152
    float* ctx = (float*)(PvH + 2097152);         // (S,B,E)    4194304 f32
    if (ws_size < (size_t)88080384) return;       // ~84 MB

    gemm_nt<0><<<dim3(16, 16, 4), 256, 0, stream>>>(memory, inputMHA, W_kv, nullptr, nullptr, Kh, Vh);
    gemm_nt<1><<<dim3(32, 8, 1),  256, 0, stream>>>(inputMHA, nullptr, W_q, u, v, quH, qvH);
    gemm_nt<2><<<dim3(16, 8, 1),  256, 0, stream>>>(posEmb, nullptr, W_p, nullptr, nullptr, PvH, nullptr);
    vt_kernel<<<dim3(32, 16, 4), 256, 0, stream>>>(Vh, VtH);
    attn_mfma<<<dim3(16, 16, 4), 256, 0, stream>>>(quH, qvH, Kh, PvH, VtH, ctx);
    gemm_nt<3><<<dim3(32, 8, 1),  256, 0, stream>>>(ctx, nullptr, W_out, inputMHA, nullptr, out, nullptr);
    ln_kernel<<<dim3(4096, 1, 1), 256, 0, stream>>>(out, ln_w, ln_b);
}

// Round 3
// 650.412 us; speedup vs baseline: 3.0534x; 2.0276x over previous
//
#include <hip/hip_runtime.h>
#include <hip/hip_bf16.h>

// Transformer-XL relative MHA. S=1024, P=1024, B=4, E=1024, H=16, I=64, J=2048.
// R2: all GEMMs on MFMA bf16 (128x128 tile, BK=64, XOR-swizzled LDS, reg-staged);
//     attn unchanged from R1 except bf16 ctx output.

typedef __bf16 bf16x8 __attribute__((ext_vector_type(8)));
typedef float f32x4 __attribute__((ext_vector_type(4)));

__device__ __forceinline__ unsigned short f2bf(float f) {
    unsigned int u = __float_as_uint(f);
    u = u + 0x7fffu + ((u >> 16) & 1u);   // RNE
    return (unsigned short)(u >> 16);
}
__device__ __forceinline__ bf16x8 ldfrag(const unsigned short* p) {
    uint4 u = *(const uint4*)p;
    return __builtin_bit_cast(bf16x8, u);
}
__device__ __forceinline__ bf16x8 castfrag(uint4 u) {
    return __builtin_bit_cast(bf16x8, u);
}

// fp32 -> bf16 flat cast; thread handles 4 elems; grid = n/1024.
__global__ __launch_bounds__(256)
void cast_kernel(const float* __restrict__ in, unsigned short* __restrict__ out)
{
    size_t i = ((size_t)blockIdx.x * 256 + threadIdx.x) * 4;
    float4 f = *(const float4*)(in + i);
    uint2 pk;
    pk.x = f2bf(f.x) | ((unsigned int)f2bf(f.y) << 16);
    pk.y = f2bf(f.z) | ((unsigned int)f2bf(f.w) << 16);
    *(uint2*)(out + i) = pk;
}

// ---------------------------------------------------------------------------
// C = A(MxK) @ W(NxK)^T, bf16 in, fp32 accum, K=1024. Tile 128x128, BK=64.
// 4 waves, each 64x64 (4x4 frags of 16x16x32). LDS [128 rows][8 slots of 16B],
// swizzle pos = slot ^ (row&7) (involution, applied on write and read).
// MODE 0: kv  -> K,V bf16 (B,H,J,I)    rows m=j*4+b, cols n: [K|V],h,i
// MODE 1: q   -> qu=q+u, qv=q+v bf16 (B,H,S,I)
// MODE 2: pv  -> Pv bf16 (H,J,I)
// MODE 3: out -> fp32 + residual, (S,B,E)
// ---------------------------------------------------------------------------
template<int MODE>
__global__ __launch_bounds__(256, 2)
void gemm_bt(const unsigned short* __restrict__ A,
             const unsigned short* __restrict__ W,
             const float* __restrict__ aux0, const float* __restrict__ aux1,
             void* __restrict__ o0, void* __restrict__ o1)
{
    __shared__ __align__(16) unsigned short As[128 * 64];
    __shared__ __align__(16) unsigned short Bs[128 * 64];
    const int tid = threadIdx.x;
    const int w = tid >> 6, lane = tid & 63;
    const int lg = lane >> 4, ln = lane & 15;
    const int wm = w >> 1, wn = w & 1;
    const int m0 = blockIdx.x * 128, n0 = blockIdx.y * 128;

    f32x4 acc[4][4];
    #pragma unroll
    for (int i = 0; i < 4; ++i)
        #pragma unroll
        for (int j = 0; j < 4; ++j) acc[i][j] = (f32x4){0.f, 0.f, 0.f, 0.f};

    const int srow = tid >> 3;                    // 0..31
    const int spos = tid & 7;                     // LDS 16B slot written
    const int sslot = spos ^ (srow & 7);          // global 16B slot loaded
    const int aoff = (ln & 7) << 4;               // read-side XOR source (row&7)*16

    for (int k0 = 0; k0 < 1024; k0 += 64) {
        __syncthreads();
        #pragma unroll
        for (int c = 0; c < 4; ++c) {
            int row = c * 32 + srow;
            uint4 va = *(const uint4*)(A + (size_t)(m0 + row) * 1024 + k0 + sslot * 8);
            *(uint4*)((char*)As + row * 128 + spos * 16) = va;
            uint4 vb = *(const uint4*)(W + (size_t)(n0 + row) * 1024 + k0 + sslot * 8);
            *(uint4*)((char*)Bs + row * 128 + spos * 16) = vb;
        }
        __syncthreads();
        #pragma unroll
        for (int kh = 0; kh < 2; ++kh) {
            bf16x8 af[4], bfr[4];
            #pragma unroll
            for (int f = 0; f < 4; ++f) {
                int ar = wm * 64 + f * 16 + ln;
                af[f] = *(const bf16x8*)((const char*)As + ar * 128 + ((((kh * 4 + lg) << 4) ^ aoff)));
                int br = wn * 64 + f * 16 + ln;
                bfr[f] = *(const bf16x8*)((const char*)Bs + br * 128 + ((((kh * 4 + lg) << 4) ^ aoff)));
            }
            #pragma unroll
            for (int i = 0; i < 4; ++i)
                #pragma unroll
                for (int j = 0; j < 4; ++j)
                    acc[i][j] = __builtin_amdgcn_mfma_f32_16x16x32_bf16(af[i], bfr[j], acc[i][j], 0, 0, 0);
        }
    }

    // epilogue: C row m = m0 + wm*64 + i*16 + 4*lg + r; col n = n0 + wn*64 + j*16 + ln
    #pragma unroll
    for (int i = 0; i < 4; ++i) {
        #pragma unroll
        for (int r = 0; r < 4; ++r) {
            int m = m0 + wm * 64 + i * 16 + 4 * lg + r;
            #pragma unroll
            for (int j = 0; j < 4; ++j) {
                int n = n0 + wn * 64 + j * 16 + ln;
                float val = acc[i][j][r];
                if (MODE == 0) {
                    int jrow = m >> 2, b = m & 3;
                    int isV = (n >= 1024);
                    int nn = n & 1023;
                    int h = nn >> 6, ii = nn & 63;
                    unsigned short* dst = (unsigned short*)(isV ? o1 : o0)
                        + (((size_t)(b * 16 + h) * 2048 + jrow) * 64 + ii);
                    *dst = f2bf(val);
                } else if (MODE == 1) {
                    int s = m >> 2, bb = m & 3;
                    int h = n >> 6, ii = n & 63;
                    size_t base = ((size_t)(bb * 16 + h) * 1024 + s) * 64 + ii;
                    ((unsigned short*)o0)[base] = f2bf(val + aux0[n]);
                    ((unsigned short*)o1)[base] = f2bf(val + aux1[n]);
                } else if (MODE == 2) {
                    int h = n >> 6, ii = n & 63;
                    ((unsigned short*)o0)[(size_t)h * 131072 + (size_t)m * 64 + ii] = f2bf(val);
                } else {
                    ((float*)o0)[(size_t)m * 1024 + n] = val + aux0[(size_t)m * 1024 + n];
                }
            }
        }
    }
}

// Transpose V (b,h,j,i) -> Vt (b,h,i,j), bf16.
__global__ __launch_bounds__(256)
void vt_kernel(const unsigned short* __restrict__ Vg, unsigned short* __restrict__ Vt)
{
    const int jt = blockIdx.x, h = blockIdx.y, b = blockIdx.z;
    const int j0 = jt << 6;
    const size_t bh = (size_t)b * 16 + h;
    const unsigned short* src = Vg + bh * 131072;
    unsigned short* dst = Vt + bh * 131072;
    __shared__ unsigned short tile[64 * 68];
    const int tid = threadIdx.x;
    #pragma unroll
    for (int q = 0; q < 4; ++q) {
        int e = tid + q * 256;
        int row = e >> 4;
        int c4 = (e & 15) << 2;
        uint2 u = *(const uint2*)(src + (size_t)(j0 + row) * 64 + c4);
        tile[(c4 + 0) * 68 + row] = (unsigned short)(u.x & 0xffff);
        tile[(c4 + 1) * 68 + row] = (unsigned short)(u.x >> 16);
        tile[(c4 + 2) * 68 + row] = (unsigned short)(u.y & 0xffff);
        tile[(c4 + 3) * 68 + row] = (unsigned short)(u.y >> 16);
    }
    __syncthreads();
    #pragma unroll
    for (int q = 0; q < 4; ++q) {
        int e = tid + q * 256;
        int i = e >> 4;
        int c4 = (e & 15) << 2;
        uint2 u;
        u.x = (unsigned int)tile[i * 68 + c4]     | ((unsigned int)tile[i * 68 + c4 + 1] << 16);
        u.y = (unsigned int)tile[i * 68 + c4 + 2] | ((unsigned int)tile[i * 68 + c4 + 3] << 16);
        *(uint2*)(dst + (size_t)i * 2048 + j0 + c4) = u;
    }
}

// ---------------------------------------------------------------------------
// MFMA flash attention (R1 structure; ctx now bf16 out).
// ---------------------------------------------------------------------------
__global__ __launch_bounds__(256, 3)
void attn_mfma(const unsigned short* __restrict__ quG, const unsigned short* __restrict__ qvG,
               const unsigned short* __restrict__ Kg, const unsigned short* __restrict__ Pvg,
               const unsigned short* __restrict__ Vt, unsigned short* __restrict__ ctx)
{
    const int st = blockIdx.x, h = blockIdx.y, b = blockIdx.z;
    const int s0 = st << 6;
    const int tid = threadIdx.x;
    const int w = tid >> 6, lane = tid & 63;
    const int lg = lane >> 4, ln = lane & 15;
    const int rowB = lg << 2;

    __shared__ float Ts[4][16 * 132];
    __shared__ unsigned short Ps[4][16 * 72];
    float* Tw = Ts[w];
    unsigned short* Pw = Ps[w];

    const size_t bh = (size_t)b * 16 + h;
    const unsigned short* quB = quG + bh * 65536;
    const unsigned short* qvB = qvG + bh * 65536;
    const unsigned short* kB  = Kg  + bh * 131072;
    const unsigned short* pvB = Pvg + (size_t)h * 131072;
    const unsigned short* vtB = Vt  + bh * 131072;

    const int srow = s0 + 16 * w + ln;
    bf16x8 quF[2], qvF[2];
    quF[0] = ldfrag(quB + (size_t)srow * 64 + 8 * lg);
    quF[1] = ldfrag(quB + (size_t)srow * 64 + 32 + 8 * lg);
    qvF[0] = ldfrag(qvB + (size_t)srow * 64 + 8 * lg);
    qvF[1] = ldfrag(qvB + (size_t)srow * 64 + 32 + 8 * lg);

    f32x4 accO[4];
    float m_run[4], l_run[4];
    #pragma unroll
    for (int r = 0; r < 4; ++r) {
        m_run[r] = -1e30f; l_run[r] = 0.f;
        accO[r] = (f32x4){0.f, 0.f, 0.f, 0.f};
    }

    const int nT = 17 + st;
    for (int t = 0; t < nT; ++t) {
        const int j0 = t << 6;
        const int pvBase = j0 + 960 - s0;

        f32x4 sC[4];
        #pragma unroll
        for (int fc = 0; fc < 4; ++fc) {
            const unsigned short* kp = kB + (size_t)(j0 + ln + 16 * fc) * 64 + 8 * lg;
            f32x4 z = {0.f, 0.f, 0.f, 0.f};
            z = __builtin_amdgcn_mfma_f32_16x16x32_bf16(quF[0], ldfrag(kp), z, 0, 0, 0);
            z = __builtin_amdgcn_mfma_f32_16x16x32_bf16(quF[1], ldfrag(kp + 32), z, 0, 0, 0);
            sC[fc] = z;
        }

        #pragma unroll
        for (int rc = 0; rc < 8; ++rc) {
            int g = pvBase + ln + 16 * rc;
            uint4 u0 = make_uint4(0, 0, 0, 0), u1 = make_uint4(0, 0, 0, 0);
            if (g < 2048) {
                const unsigned short* pp = pvB + (size_t)g * 64 + 8 * lg;
                u0 = *(const uint4*)pp;
                u1 = *(const uint4*)(pp + 32);
            }
            f32x4 z = {0.f, 0.f, 0.f, 0.f};
            z = __builtin_amdgcn_mfma_f32_16x16x32_bf16(qvF[0], castfrag(u0), z, 0, 0, 0);
            z = __builtin_amdgcn_mfma_f32_16x16x32_bf16(qvF[1], castfrag(u1), z, 0, 0, 0);
            #pragma unroll
            for (int r = 0; r < 4; ++r)
                Tw[(rowB + r) * 132 + ln + 16 * rc] = z[r];
        }

        float sc[4][4];
        #pragma unroll
        for (int fc = 0; fc < 4; ++fc) {
            int jc = ln + 16 * fc;
            int j_abs = j0 + jc;
            #pragma unroll
            for (int r = 0; r < 4; ++r) {
                int s_loc = 16 * w + rowB + r;
                int rr = jc - s_loc + 63;
                float vv = (sC[fc][r] + Tw[(rowB + r) * 132 + rr]) * 0.125f;
                if (j_abs > 1024 + s0 + s_loc) vv = -1e30f;
                sc[fc][r] = vv;
            }
        }

        #pragma unroll
        for (int r = 0; r < 4; ++r) {
            float mt = fmaxf(fmaxf(sc[0][r], sc[1][r]), fmaxf(sc[2][r], sc[3][r]));
            mt = fmaxf(mt, __shfl_xor(mt, 1, 64));
            mt = fmaxf(mt, __shfl_xor(mt, 2, 64));
            mt = fmaxf(mt, __shfl_xor(mt, 4, 64));
            mt = fmaxf(mt, __shfl_xor(mt, 8, 64));
            float mn = fmaxf(m_run[r], mt);
            float al = __expf(m_run[r] - mn);
            m_run[r] = mn;
            float rs = 0.f;
            #pragma unroll
            for (int fc = 0; fc < 4; ++fc) {
                float p = __expf(sc[fc][r] - mn);
                rs += p;
                Pw[(rowB + r) * 72 + ln + 16 * fc] = f2bf(p);
            }
            rs += __shfl_xor(rs, 1, 64);
            rs += __shfl_xor(rs, 2, 64);
            rs += __shfl_xor(rs, 4, 64);
            rs += __shfl_xor(rs, 8, 64);
            l_run[r] = l_run[r] * al + rs;
            #pragma unroll
            for (int fc = 0; fc < 4; ++fc) accO[fc][r] *= al;
        }

        bf16x8 pa0 = ldfrag(Pw + ln * 72 + 8 * lg);
        bf16x8 pa1 = ldfrag(Pw + ln * 72 + 32 + 8 * lg);

        #pragma unroll
        for (int fc = 0; fc < 4; ++fc) {
            const unsigned short* vp = vtB + (size_t)(ln + 16 * fc) * 2048 + j0 + 8 * lg;
            accO[fc] = __builtin_amdgcn_mfma_f32_16x16x32_bf16(pa0, ldfrag(vp), accO[fc], 0, 0, 0);
            accO[fc] = __builtin_amdgcn_mfma_f32_16x16x32_bf16(pa1, ldfrag(vp + 32), accO[fc], 0, 0, 0);
        }
    }

    #pragma unroll
    for (int r = 0; r < 4; ++r) {
        float inv = 1.0f / l_run[r];
        #pragma unroll
        for (int fc = 0; fc < 4; ++fc) {
            size_t dst = ((size_t)(s0 + 16 * w + rowB + r) * 4 + b) * 1024 + h * 64 + ln + 16 * fc;
            ctx[dst] = f2bf(accO[fc][r] * inv);
        }
    }
}

// In-place LayerNorm over E=1024 per row.
__global__ __launch_bounds__(256)
void ln_kernel(float* __restrict__ io, const float* __restrict__ w, const float* __restrict__ bvec)
{
    int row = blockIdx.x;
    float* p = io + (size_t)row * 1024;
    int tid = threadIdx.x;
    float4 v = *(const float4*)(p + tid * 4);
    float s  = v.x + v.y + v.z + v.w;
    float s2 = v.x * v.x + v.y * v.y + v.z * v.z + v.w * v.w;
    #pragma unroll
    for (int off = 1; off < 64; off <<= 1) {
        s  += __shfl_xor(s,  off, 64);
        s2 += __shfl_xor(s2, off, 64);
    }
    __shared__ float red[8];
    int wv = tid >> 6;
    if ((tid & 63) == 0) { red[wv] = s; red[wv + 4] = s2; }
    __syncthreads();
    s  = red[0] + red[1] + red[2] + red[3];
    s2 = red[4] + red[5] + red[6] + red[7];
    float mu  = s * (1.0f / 1024.0f);
    float var = s2 * (1.0f / 1024.0f) - mu * mu;
    float rstd = rsqrtf(var + 1e-5f);
    float4 w4 = *(const float4*)(w + tid * 4);
    float4 b4 = *(const float4*)(bvec + tid * 4);
    float4 o;
    o.x = (v.x - mu) * rstd * w4.x + b4.x;
    o.y = (v.y - mu) * rstd * w4.y + b4.y;
    o.z = (v.z - mu) * rstd * w4.z + b4.z;
    o.w = (v.w - mu) * rstd * w4.w + b4.w;
    *(float4*)(p + tid * 4) = o;
}

extern "C" void kernel_launch(void* const* d_in, const int* in_sizes, int n_in,
                              void* d_out, int out_size, void* d_ws, size_t ws_size,
                              hipStream_t stream)
{
    const float* inputMHA = (const float*)d_in[0];
    const float* posEmb   = (const float*)d_in[1];
    const float* memory   = (const float*)d_in[2];
    const float* u        = (const float*)d_in[3];
    const float* v        = (const float*)d_in[4];
    const float* W_kv     = (const float*)d_in[5];
    const float* W_q      = (const float*)d_in[6];
    const float* W_p      = (const float*)d_in[7];
    const float* W_out    = (const float*)d_in[8];
    const float* ln_w     = (const float*)d_in[9];
    const float* ln_b     = (const float*)d_in[10];
    float* out = (float*)d_out;

    unsigned short* wsh  = (unsigned short*)d_ws;
    unsigned short* Kh   = wsh;                    // (B,H,J,I)  8388608
    unsigned short* Vh   = Kh   + 8388608;
    unsigned short* VtH  = Vh   + 8388608;         // (B,H,I,J)
    unsigned short* quH  = VtH  + 8388608;         // (B,H,S,I)  4194304
    unsigned short* qvH  = quH  + 4194304;
    unsigned short* PvH  = qvH  + 4194304;         // (H,J,I)    2097152
    unsigned short* Xh   = PvH  + 2097152;         // (J,B,E)    8388608 (mem | input)
    unsigned short* Ph   = Xh   + 8388608;         // (J,E)      2097152
    unsigned short* Wkvh = Ph   + 2097152;         // 2097152
    unsigned short* Wqh  = Wkvh + 2097152;         // 1048576
    unsigned short* Wph  = Wqh  + 1048576;
    unsigned short* Woh  = Wph  + 1048576;
    unsigned short* ctxh = Woh  + 1048576;         // (S,B,E)    4194304
    if (ws_size < (size_t)111149056) return;       // ~106 MB

    // casts (fp32 -> bf16)
    cast_kernel<<<dim3(4096), 256, 0, stream>>>(memory,   Xh);
    cast_kernel<<<dim3(4096), 256, 0, stream>>>(inputMHA, Xh + 4194304);
    cast_kernel<<<dim3(2048), 256, 0, stream>>>(posEmb,   Ph);
    cast_kernel<<<dim3(2048), 256, 0, stream>>>(W_kv,     Wkvh);
    cast_kernel<<<dim3(1024), 256, 0, stream>>>(W_q,      Wqh);
    cast_kernel<<<dim3(1024), 256, 0, stream>>>(W_p,      Wph);
    cast_kernel<<<dim3(1024), 256, 0, stream>>>(W_out,    Woh);

    gemm_bt<0><<<dim3(64, 16), 256, 0, stream>>>(Xh, Wkvh, nullptr, nullptr, Kh, Vh);
    gemm_bt<1><<<dim3(32, 8),  256, 0, stream>>>(Xh + 4194304, Wqh, u, v, quH, qvH);
    gemm_bt<2><<<dim3(16, 8),  256, 0, stream>>>(Ph, Wph, nullptr, nullptr, PvH, nullptr);
    vt_kernel<<<dim3(32, 16, 4), 256, 0, stream>>>(Vh, VtH);
    attn_mfma<<<dim3(16, 16, 4), 256, 0, stream>>>(quH, qvH, Kh, PvH, VtH, ctxh);
    gemm_bt<3><<<dim3(32, 8),  256, 0, stream>>>(ctxh, Woh, inputMHA, nullptr, out, nullptr);
    ln_kernel<<<dim3(4096), 256, 0, stream>>>(out, ln_w, ln_b);
}

// Round 4
// 642.307 us; speedup vs baseline: 3.0919x; 1.0126x over previous
//
#include <hip/hip_runtime.h>
#include <hip/hip_bf16.h>

// Transformer-XL relative MHA. S=1024, P=1024, B=4, E=1024, H=16, I=64, J=2048.
// R3: attn rewritten: KVBLK=128, per-wave pos window (143 rows), transposed
// packed-bf16 T, XOR-swizzled bf16 P, 4 blocks/CU, no __syncthreads.

typedef __bf16 bf16x8 __attribute__((ext_vector_type(8)));
typedef float f32x4 __attribute__((ext_vector_type(4)));

__device__ __forceinline__ unsigned short f2bf(float f) {
    unsigned int u = __float_as_uint(f);
    u = u + 0x7fffu + ((u >> 16) & 1u);   // RNE
    return (unsigned short)(u >> 16);
}
__device__ __forceinline__ float bf2f(unsigned short s) {
    return __uint_as_float((unsigned int)s << 16);
}
__device__ __forceinline__ bf16x8 ldfrag(const unsigned short* p) {
    uint4 u = *(const uint4*)p;
    return __builtin_bit_cast(bf16x8, u);
}
__device__ __forceinline__ bf16x8 castfrag(uint4 u) {
    return __builtin_bit_cast(bf16x8, u);
}

// fp32 -> bf16 flat cast; thread handles 4 elems; grid = n/1024.
__global__ __launch_bounds__(256)
void cast_kernel(const float* __restrict__ in, unsigned short* __restrict__ out)
{
    size_t i = ((size_t)blockIdx.x * 256 + threadIdx.x) * 4;
    float4 f = *(const float4*)(in + i);
    uint2 pk;
    pk.x = f2bf(f.x) | ((unsigned int)f2bf(f.y) << 16);
    pk.y = f2bf(f.z) | ((unsigned int)f2bf(f.w) << 16);
    *(uint2*)(out + i) = pk;
}

// ---------------------------------------------------------------------------
// C = A(MxK) @ W(NxK)^T, bf16 in, fp32 accum, K=1024. Tile 128x128, BK=64.
// ---------------------------------------------------------------------------
template<int MODE>
__global__ __launch_bounds__(256, 2)
void gemm_bt(const unsigned short* __restrict__ A,
             const unsigned short* __restrict__ W,
             const float* __restrict__ aux0, const float* __restrict__ aux1,
             void* __restrict__ o0, void* __restrict__ o1)
{
    __shared__ __align__(16) unsigned short As[128 * 64];
    __shared__ __align__(16) unsigned short Bs[128 * 64];
    const int tid = threadIdx.x;
    const int w = tid >> 6, lane = tid & 63;
    const int lg = lane >> 4, ln = lane & 15;
    const int wm = w >> 1, wn = w & 1;
    const int m0 = blockIdx.x * 128, n0 = blockIdx.y * 128;

    f32x4 acc[4][4];
    #pragma unroll
    for (int i = 0; i < 4; ++i)
        #pragma unroll
        for (int j = 0; j < 4; ++j) acc[i][j] = (f32x4){0.f, 0.f, 0.f, 0.f};

    const int srow = tid >> 3;
    const int spos = tid & 7;
    const int sslot = spos ^ (srow & 7);
    const int aoff = (ln & 7) << 4;

    for (int k0 = 0; k0 < 1024; k0 += 64) {
        __syncthreads();
        #pragma unroll
        for (int c = 0; c < 4; ++c) {
            int row = c * 32 + srow;
            uint4 va = *(const uint4*)(A + (size_t)(m0 + row) * 1024 + k0 + sslot * 8);
            *(uint4*)((char*)As + row * 128 + spos * 16) = va;
            uint4 vb = *(const uint4*)(W + (size_t)(n0 + row) * 1024 + k0 + sslot * 8);
            *(uint4*)((char*)Bs + row * 128 + spos * 16) = vb;
        }
        __syncthreads();
        #pragma unroll
        for (int kh = 0; kh < 2; ++kh) {
            bf16x8 af[4], bfr[4];
            #pragma unroll
            for (int f = 0; f < 4; ++f) {
                int ar = wm * 64 + f * 16 + ln;
                af[f] = *(const bf16x8*)((const char*)As + ar * 128 + ((((kh * 4 + lg) << 4) ^ aoff)));
                int br = wn * 64 + f * 16 + ln;
                bfr[f] = *(const bf16x8*)((const char*)Bs + br * 128 + ((((kh * 4 + lg) << 4) ^ aoff)));
            }
            #pragma unroll
            for (int i = 0; i < 4; ++i)
                #pragma unroll
                for (int j = 0; j < 4; ++j)
                    acc[i][j] = __builtin_amdgcn_mfma_f32_16x16x32_bf16(af[i], bfr[j], acc[i][j], 0, 0, 0);
        }
    }

    #pragma unroll
    for (int i = 0; i < 4; ++i) {
        #pragma unroll
        for (int r = 0; r < 4; ++r) {
            int m = m0 + wm * 64 + i * 16 + 4 * lg + r;
            #pragma unroll
            for (int j = 0; j < 4; ++j) {
                int n = n0 + wn * 64 + j * 16 + ln;
                float val = acc[i][j][r];
                if (MODE == 0) {
                    int jrow = m >> 2, b = m & 3;
                    int isV = (n >= 1024);
                    int nn = n & 1023;
                    int h = nn >> 6, ii = nn & 63;
                    unsigned short* dst = (unsigned short*)(isV ? o1 : o0)
                        + (((size_t)(b * 16 + h) * 2048 + jrow) * 64 + ii);
                    *dst = f2bf(val);
                } else if (MODE == 1) {
                    int s = m >> 2, bb = m & 3;
                    int h = n >> 6, ii = n & 63;
                    size_t base = ((size_t)(bb * 16 + h) * 1024 + s) * 64 + ii;
                    ((unsigned short*)o0)[base] = f2bf(val + aux0[n]);
                    ((unsigned short*)o1)[base] = f2bf(val + aux1[n]);
                } else if (MODE == 2) {
                    int h = n >> 6, ii = n & 63;
                    ((unsigned short*)o0)[(size_t)h * 131072 + (size_t)m * 64 + ii] = f2bf(val);
                } else {
                    ((float*)o0)[(size_t)m * 1024 + n] = val + aux0[(size_t)m * 1024 + n];
                }
            }
        }
    }
}

// Transpose V (b,h,j,i) -> Vt (b,h,i,j), bf16.
__global__ __launch_bounds__(256)
void vt_kernel(const unsigned short* __restrict__ Vg, unsigned short* __restrict__ Vt)
{
    const int jt = blockIdx.x, h = blockIdx.y, b = blockIdx.z;
    const int j0 = jt << 6;
    const size_t bh = (size_t)b * 16 + h;
    const unsigned short* src = Vg + bh * 131072;
    unsigned short* dst = Vt + bh * 131072;
    __shared__ unsigned short tile[64 * 68];
    const int tid = threadIdx.x;
    #pragma unroll
    for (int q = 0; q < 4; ++q) {
        int e = tid + q * 256;
        int row = e >> 4;
        int c4 = (e & 15) << 2;
        uint2 u = *(const uint2*)(src + (size_t)(j0 + row) * 64 + c4);
        tile[(c4 + 0) * 68 + row] = (unsigned short)(u.x & 0xffff);
        tile[(c4 + 1) * 68 + row] = (unsigned short)(u.x >> 16);
        tile[(c4 + 2) * 68 + row] = (unsigned short)(u.y & 0xffff);
        tile[(c4 + 3) * 68 + row] = (unsigned short)(u.y >> 16);
    }
    __syncthreads();
    #pragma unroll
    for (int q = 0; q < 4; ++q) {
        int e = tid + q * 256;
        int i = e >> 4;
        int c4 = (e & 15) << 2;
        uint2 u;
        u.x = (unsigned int)tile[i * 68 + c4]     | ((unsigned int)tile[i * 68 + c4 + 1] << 16);
        u.y = (unsigned int)tile[i * 68 + c4 + 2] | ((unsigned int)tile[i * 68 + c4 + 3] << 16);
        *(uint2*)(dst + (size_t)i * 2048 + j0 + c4) = u;
    }
}

// ---------------------------------------------------------------------------
// MFMA flash attention, KVBLK=128 per phase.
// Per wave (16 q-rows): content QK^T (8 frags x2), pos-GEMM over per-wave
// 143-row Pv window (9 frags x2) -> transposed packed-bf16 T in LDS ->
// diagonal gather; online softmax; P -> XOR-swizzled bf16 LDS -> A-frags;
// PV with pre-transposed Vt. All LDS wave-private; no __syncthreads.
// ---------------------------------------------------------------------------
__global__ __launch_bounds__(256, 4)
void attn_mfma(const unsigned short* __restrict__ quG, const unsigned short* __restrict__ qvG,
               const unsigned short* __restrict__ Kg, const unsigned short* __restrict__ Pvg,
               const unsigned short* __restrict__ Vt, unsigned short* __restrict__ ctx)
{
    const int st = blockIdx.x, h = blockIdx.y, b = blockIdx.z;
    const int s0 = st << 6;
    const int tid = threadIdx.x;
    const int w = tid >> 6, lane = tid & 63;
    const int lg = lane >> 4, ln = lane & 15;
    const int rowB = lg << 2;

    __shared__ unsigned short Ts[4][144 * 20];   // [wave][wc*20 + sr], bf16, transposed
    __shared__ unsigned short Ps[4][16 * 128];   // [wave][sr*128 + (jc ^ ((sr&7)<<3))]
    unsigned short* Tw = Ts[w];
    unsigned short* Pw = Ps[w];

    const size_t bh = (size_t)b * 16 + h;
    const unsigned short* quB = quG + bh * 65536;
    const unsigned short* qvB = qvG + bh * 65536;
    const unsigned short* kB  = Kg  + bh * 131072;
    const unsigned short* pvB = Pvg + (size_t)h * 131072;
    const unsigned short* vtB = Vt  + bh * 131072;

    const int srow = s0 + 16 * w + ln;
    bf16x8 quF[2], qvF[2];
    quF[0] = ldfrag(quB + (size_t)srow * 64 + 8 * lg);
    quF[1] = ldfrag(quB + (size_t)srow * 64 + 32 + 8 * lg);
    qvF[0] = ldfrag(qvB + (size_t)srow * 64 + 8 * lg);
    qvF[1] = ldfrag(qvB + (size_t)srow * 64 + 32 + 8 * lg);

    f32x4 accO[4];
    float m_run[4], l_run[4];
    #pragma unroll
    for (int r = 0; r < 4; ++r) {
        m_run[r] = -1e30f; l_run[r] = 0.f;
        accO[r] = (f32x4){0.f, 0.f, 0.f, 0.f};
    }

    const int nT = (1215 + 64 * st) >> 7;
    for (int t = 0; t < nT; ++t) {
        const int j0 = t << 7;
        const int baseW = j0 + 1008 - s0 - 16 * w;   // >= 0 always

        // content scores: 8 col-frags of 16 keys
        f32x4 sC[8];
        #pragma unroll
        for (int fc = 0; fc < 8; ++fc) {
            const unsigned short* kp = kB + (size_t)(j0 + ln + 16 * fc) * 64 + 8 * lg;
            f32x4 z = {0.f, 0.f, 0.f, 0.f};
            z = __builtin_amdgcn_mfma_f32_16x16x32_bf16(quF[0], ldfrag(kp), z, 0, 0, 0);
            z = __builtin_amdgcn_mfma_f32_16x16x32_bf16(quF[1], ldfrag(kp + 32), z, 0, 0, 0);
            sC[fc] = z;
        }

        // pos-GEMM over per-wave window [baseW, baseW+143] -> transposed bf16 T
        #pragma unroll
        for (int rc = 0; rc < 9; ++rc) {
            int wc = ln + 16 * rc;                 // 0..143
            int g = baseW + wc;
            uint4 u0 = make_uint4(0, 0, 0, 0), u1 = make_uint4(0, 0, 0, 0);
            if (g < 2048) {
                const unsigned short* pp = pvB + (size_t)g * 64 + 8 * lg;
                u0 = *(const uint4*)pp;
                u1 = *(const uint4*)(pp + 32);
            }
            f32x4 z = {0.f, 0.f, 0.f, 0.f};
            z = __builtin_amdgcn_mfma_f32_16x16x32_bf16(qvF[0], castfrag(u0), z, 0, 0, 0);
            z = __builtin_amdgcn_mfma_f32_16x16x32_bf16(qvF[1], castfrag(u1), z, 0, 0, 0);
            uint2 pk;
            pk.x = f2bf(z[0]) | ((unsigned int)f2bf(z[1]) << 16);
            pk.y = f2bf(z[2]) | ((unsigned int)f2bf(z[3]) << 16);
            *(uint2*)&Tw[wc * 20 + rowB] = pk;     // rows rowB..rowB+3 of col wc
        }

        // gather shifted pos + combine + scale + mask
        float sc[8][4];
        #pragma unroll
        for (int fc = 0; fc < 8; ++fc) {
            int jc = ln + 16 * fc;
            int j_abs = j0 + jc;
            #pragma unroll
            for (int r = 0; r < 4; ++r) {
                int sr = rowB + r;                 // 0..15 within wave
                int rr = jc - sr + 15;             // window col, 0..142
                float vv = (sC[fc][r] + bf2f(Tw[rr * 20 + sr])) * 0.125f;
                if (j_abs > 1024 + s0 + 16 * w + sr) vv = -1e30f;
                sc[fc][r] = vv;
            }
        }

        // online softmax per C-row r (16 ln lanes hold 8 cols each)
        #pragma unroll
        for (int r = 0; r < 4; ++r) {
            int sr = rowB + r;
            float mt = sc[0][r];
            #pragma unroll
            for (int fc = 1; fc < 8; ++fc) mt = fmaxf(mt, sc[fc][r]);
            mt = fmaxf(mt, __shfl_xor(mt, 1, 64));
            mt = fmaxf(mt, __shfl_xor(mt, 2, 64));
            mt = fmaxf(mt, __shfl_xor(mt, 4, 64));
            mt = fmaxf(mt, __shfl_xor(mt, 8, 64));
            float mn = fmaxf(m_run[r], mt);
            float al = __expf(m_run[r] - mn);
            m_run[r] = mn;
            float rs = 0.f;
            #pragma unroll
            for (int fc = 0; fc < 8; ++fc) {
                float p = __expf(sc[fc][r] - mn);
                rs += p;
                int jc = ln + 16 * fc;
                Pw[sr * 128 + (jc ^ ((sr & 7) << 3))] = f2bf(p);
            }
            rs += __shfl_xor(rs, 1, 64);
            rs += __shfl_xor(rs, 2, 64);
            rs += __shfl_xor(rs, 4, 64);
            rs += __shfl_xor(rs, 8, 64);
            l_run[r] = l_run[r] * al + rs;
            #pragma unroll
            for (int fc = 0; fc < 4; ++fc) accO[fc][r] *= al;
        }

        // P A-frags (row ln, k = 32*ks + 8*lg, XOR-swizzled read)
        bf16x8 pa[4];
        #pragma unroll
        for (int ks = 0; ks < 4; ++ks)
            pa[ks] = ldfrag(&Pw[ln * 128 + ((32 * ks + 8 * lg) ^ ((ln & 7) << 3))]);

        // PV with transposed Vt
        #pragma unroll
        for (int fc = 0; fc < 4; ++fc) {
            const unsigned short* vp = vtB + (size_t)(ln + 16 * fc) * 2048 + j0 + 8 * lg;
            #pragma unroll
            for (int ks = 0; ks < 4; ++ks)
                accO[fc] = __builtin_amdgcn_mfma_f32_16x16x32_bf16(pa[ks], ldfrag(vp + 32 * ks), accO[fc], 0, 0, 0);
        }
    }

    #pragma unroll
    for (int r = 0; r < 4; ++r) {
        float inv = 1.0f / l_run[r];
        #pragma unroll
        for (int fc = 0; fc < 4; ++fc) {
            size_t dst = ((size_t)(s0 + 16 * w + rowB + r) * 4 + b) * 1024 + h * 64 + ln + 16 * fc;
            ctx[dst] = f2bf(accO[fc][r] * inv);
        }
    }
}

// In-place LayerNorm over E=1024 per row.
__global__ __launch_bounds__(256)
void ln_kernel(float* __restrict__ io, const float* __restrict__ w, const float* __restrict__ bvec)
{
    int row = blockIdx.x;
    float* p = io + (size_t)row * 1024;
    int tid = threadIdx.x;
    float4 v = *(const float4*)(p + tid * 4);
    float s  = v.x + v.y + v.z + v.w;
    float s2 = v.x * v.x + v.y * v.y + v.z * v.z + v.w * v.w;
    #pragma unroll
    for (int off = 1; off < 64; off <<= 1) {
        s  += __shfl_xor(s,  off, 64);
        s2 += __shfl_xor(s2, off, 64);
    }
    __shared__ float red[8];
    int wv = tid >> 6;
    if ((tid & 63) == 0) { red[wv] = s; red[wv + 4] = s2; }
    __syncthreads();
    s  = red[0] + red[1] + red[2] + red[3];
    s2 = red[4] + red[5] + red[6] + red[7];
    float mu  = s * (1.0f / 1024.0f);
    float var = s2 * (1.0f / 1024.0f) - mu * mu;
    float rstd = rsqrtf(var + 1e-5f);
    float4 w4 = *(const float4*)(w + tid * 4);
    float4 b4 = *(const float4*)(bvec + tid * 4);
    float4 o;
    o.x = (v.x - mu) * rstd * w4.x + b4.x;
    o.y = (v.y - mu) * rstd * w4.y + b4.y;
    o.z = (v.z - mu) * rstd * w4.z + b4.z;
    o.w = (v.w - mu) * rstd * w4.w + b4.w;
    *(float4*)(p + tid * 4) = o;
}

extern "C" void kernel_launch(void* const* d_in, const int* in_sizes, int n_in,
                              void* d_out, int out_size, void* d_ws, size_t ws_size,
                              hipStream_t stream)
{
    const float* inputMHA = (const float*)d_in[0];
    const float* posEmb   = (const float*)d_in[1];
    const float* memory   = (const float*)d_in[2];
    const float* u        = (const float*)d_in[3];
    const float* v        = (const float*)d_in[4];
    const float* W_kv     = (const float*)d_in[5];
    const float* W_q      = (const float*)d_in[6];
    const float* W_p      = (const float*)d_in[7];
    const float* W_out    = (const float*)d_in[8];
    const float* ln_w     = (const float*)d_in[9];
    const float* ln_b     = (const float*)d_in[10];
    float* out = (float*)d_out;

    unsigned short* wsh  = (unsigned short*)d_ws;
    unsigned short* Kh   = wsh;                    // (B,H,J,I)  8388608
    unsigned short* Vh   = Kh   + 8388608;
    unsigned short* VtH  = Vh   + 8388608;         // (B,H,I,J)
    unsigned short* quH  = VtH  + 8388608;         // (B,H,S,I)  4194304
    unsigned short* qvH  = quH  + 4194304;
    unsigned short* PvH  = qvH  + 4194304;         // (H,J,I)    2097152
    unsigned short* Xh   = PvH  + 2097152;         // (J,B,E)    8388608 (mem | input)
    unsigned short* Ph   = Xh   + 8388608;         // (J,E)      2097152
    unsigned short* Wkvh = Ph   + 2097152;         // 2097152
    unsigned short* Wqh  = Wkvh + 2097152;         // 1048576
    unsigned short* Wph  = Wqh  + 1048576;
    unsigned short* Woh  = Wph  + 1048576;
    unsigned short* ctxh = Woh  + 1048576;         // (S,B,E)    4194304
    if (ws_size < (size_t)111149056) return;

    cast_kernel<<<dim3(4096), 256, 0, stream>>>(memory,   Xh);
    cast_kernel<<<dim3(4096), 256, 0, stream>>>(inputMHA, Xh + 4194304);
    cast_kernel<<<dim3(2048), 256, 0, stream>>>(posEmb,   Ph);
    cast_kernel<<<dim3(2048), 256, 0, stream>>>(W_kv,     Wkvh);
    cast_kernel<<<dim3(1024), 256, 0, stream>>>(W_q,      Wqh);
    cast_kernel<<<dim3(1024), 256, 0, stream>>>(W_p,      Wph);
    cast_kernel<<<dim3(1024), 256, 0, stream>>>(W_out,    Woh);

    gemm_bt<0><<<dim3(64, 16), 256, 0, stream>>>(Xh, Wkvh, nullptr, nullptr, Kh, Vh);
    gemm_bt<1><<<dim3(32, 8),  256, 0, stream>>>(Xh + 4194304, Wqh, u, v, quH, qvH);
    gemm_bt<2><<<dim3(16, 8),  256, 0, stream>>>(Ph, Wph, nullptr, nullptr, PvH, nullptr);
    vt_kernel<<<dim3(32, 16, 4), 256, 0, stream>>>(Vh, VtH);
    attn_mfma<<<dim3(16, 16, 4), 256, 0, stream>>>(quH, qvH, Kh, PvH, VtH, ctxh);
    gemm_bt<3><<<dim3(32, 8),  256, 0, stream>>>(ctxh, Woh, inputMHA, nullptr, out, nullptr);
    ln_kernel<<<dim3(4096), 256, 0, stream>>>(out, ln_w, ln_b);
}